// Round 6
// baseline (1523.456 us; speedup 1.0000x reference)
//
#include <hip/hip_runtime.h>
#include <hip/hip_bf16.h>
#include <stdint.h>
#include <math.h>

#define T_TOK 4096
#define HD    1024
#define NE    16
#define FF    2816
#define TOPK  8
#define NPAIR (T_TOK*TOPK)

typedef __attribute__((ext_vector_type(8))) __bf16 bf16x8;
typedef __attribute__((ext_vector_type(4))) float  f32x4;
typedef __attribute__((ext_vector_type(8))) unsigned short u16x8;

__device__ __forceinline__ unsigned short f2bf(float x){
  union { float f; unsigned u; } c; c.f = x;
  unsigned r = (c.u + 0x7FFFu + ((c.u >> 16) & 1u)) >> 16;
  return (unsigned short)r;
}
__device__ __forceinline__ float bf2f(unsigned short h){
  union { unsigned u; float f; } c; c.u = ((unsigned)h) << 16; return c.f;
}
__device__ __forceinline__ u16x8 pack8(float4 a, float4 b){
  u16x8 p;
  p[0]=f2bf(a.x); p[1]=f2bf(a.y); p[2]=f2bf(a.z); p[3]=f2bf(a.w);
  p[4]=f2bf(b.x); p[5]=f2bf(b.y); p[6]=f2bf(b.z); p[7]=f2bf(b.w);
  return p;
}

// async global->LDS, 16B per lane
__device__ __forceinline__ void gload16(const void* src, void* lds_dst){
  __builtin_amdgcn_global_load_lds((const __attribute__((address_space(1))) unsigned int*)src,
                                   (__attribute__((address_space(3))) unsigned int*)lds_dst,
                                   16, 0, 0);
}

// ---------------- router ----------------
__global__ __launch_bounds__(256) void router_kernel(
    const float* __restrict__ x, const float* __restrict__ rw,
    unsigned short* __restrict__ xbf, int* __restrict__ topk_idx, float* __restrict__ topk_w)
{
  __shared__ float xs[HD];
  __shared__ float lg[NE];
  const int t   = blockIdx.x;
  const int tid = threadIdx.x;
  const int lane = tid & 63;
  const int wid  = tid >> 6;

  float4 v = ((const float4*)(x + (size_t)t*HD))[tid];
  ((float4*)xs)[tid] = v;
  ushort4 o;
  o.x = f2bf(v.x); o.y = f2bf(v.y); o.z = f2bf(v.z); o.w = f2bf(v.w);
  ((ushort4*)(xbf + (size_t)t*HD))[tid] = o;
  __syncthreads();

  for (int ee = 0; ee < 4; ++ee){
    int e = wid*4 + ee;
    const float* w = rw + (size_t)e*HD;
    float p = 0.f;
    for (int j = lane; j < HD; j += 64) p += xs[j] * w[j];
    #pragma unroll
    for (int offs = 32; offs; offs >>= 1) p += __shfl_xor(p, offs, 64);
    if (lane == 0) lg[e] = p;
  }
  __syncthreads();

  if (tid == 0){
    float vals[NE];
    #pragma unroll
    for (int e = 0; e < NE; ++e) vals[e] = lg[e];
    int   idx[TOPK]; float tv[TOPK];
    for (int k = 0; k < TOPK; ++k){
      int bi = 0; float bv = -3.4e38f;
      for (int e = 0; e < NE; ++e) if (vals[e] > bv){ bv = vals[e]; bi = e; }
      idx[k] = bi; tv[k] = bv; vals[bi] = -3.4e38f;
    }
    float m = tv[0];
    float ex[TOPK]; float s = 0.f;
    for (int k = 0; k < TOPK; ++k){ ex[k] = expf(tv[k] - m); s += ex[k]; }
    float inv = 1.f / s;
    for (int k = 0; k < TOPK; ++k){
      topk_idx[t*TOPK + k] = idx[k];
      topk_w [t*TOPK + k] = ex[k] * inv;
    }
  }
}

// ---------------- deterministic token lists (derives cnt+offs itself) ----------------
__global__ __launch_bounds__(256) void lists_kernel(
    const int* __restrict__ topk_idx,
    int* __restrict__ rows, int* __restrict__ slot_of,
    int* __restrict__ cnt, int* __restrict__ offs_out)
{
  const int e = blockIdx.x;
  const int tid = threadIdx.x;
  const int lane = tid & 63;
  const int wid  = tid >> 6;

  __shared__ int wred[4];
  __shared__ int wred2[4];
  __shared__ int soff;

  int nlt = 0, ceq = 0;
  for (int t = tid; t < T_TOK; t += 256){
    #pragma unroll
    for (int k = 0; k < TOPK; ++k){
      int vv = topk_idx[t*TOPK + k];
      nlt += (vv < e) ? 1 : 0;
      ceq += (vv == e) ? 1 : 0;
    }
  }
  #pragma unroll
  for (int offs = 32; offs; offs >>= 1){
    nlt += __shfl_xor(nlt, offs, 64);
    ceq += __shfl_xor(ceq, offs, 64);
  }
  if (lane == 0){ wred[wid] = nlt; wred2[wid] = ceq; }
  __syncthreads();
  if (tid == 0){
    int off = wred[0] + wred[1] + wred[2] + wred[3];
    int c   = wred2[0] + wred2[1] + wred2[2] + wred2[3];
    offs_out[e] = off;
    cnt[e] = c;
    soff = off;
  }
  __syncthreads();
  const int off = soff;

  __shared__ int wc[4];
  int base = 0;
  for (int c0 = 0; c0 < T_TOK; c0 += 256){
    int t = c0 + tid;
    int kpos = -1;
    #pragma unroll
    for (int k = 0; k < TOPK; ++k) if (topk_idx[t*TOPK + k] == e) kpos = k;
    bool f = (kpos >= 0);
    unsigned long long m = __ballot(f);
    if (lane == 0) wc[wid] = __popcll(m);
    __syncthreads();
    int p = base;
    for (int w = 0; w < wid; ++w) p += wc[w];
    p += __popcll(m & ((1ULL << lane) - 1ULL));
    if (f){
      rows[off + p] = t;
      slot_of[t*TOPK + kpos] = off + p;
    }
    int tot = wc[0] + wc[1] + wc[2] + wc[3];
    __syncthreads();
    base += tot;
  }
}

// ---------------- stage-1: h = silu(x@gateT) * (x@upT), grouped ----------------
// BM=128 x BF=64, BK=64, 4 waves. A (bf16 gathered) via global_load_lds with
// pre-swizzled source; B (fp32 weights) via reg-staging: global fp32 load ->
// RNE cvt -> ds_write_b128 to the swizzled slot. No separate convert pass.
__global__ __launch_bounds__(256, 3) void gemm_gateup(
    const unsigned short* __restrict__ xbf,
    const float* __restrict__ gw,
    const float* __restrict__ uw,
    const int* __restrict__ rows, const int* __restrict__ cnt, const int* __restrict__ offs,
    unsigned short* __restrict__ hbuf)
{
  const int cpx = gridDim.x >> 3;
  const int bid = blockIdx.x;
  const int nid = (bid & 7) * cpx + (bid >> 3);
  const int mb   = nid & 31;
  const int rest = nid >> 5;
  const int nb   = rest % (FF/64);
  const int e    = rest / (FF/64);

  const int c  = cnt[e];
  const int m0 = mb * 128;
  if (m0 >= c) return;
  const int n0 = nb * 64;
  const int off_e = offs[e];

  __shared__ unsigned short As[128*64];
  __shared__ unsigned short Bg[64*64];
  __shared__ unsigned short Bu[64*64];

  const int tid  = threadIdx.x;
  const int lane = tid & 63;
  const int wid  = tid >> 6;
  const int ar = lane & 15;
  const int kb = lane >> 4;
  const int wm = wid >> 1;
  const int wn = wid & 1;

  // A: chunk cj = j*256+tid -> row cj>>3, phys slot cj&7 holds logical (cj&7)^(row&7)
  const unsigned short* asrc[4];
  #pragma unroll
  for (int j = 0; j < 4; ++j){
    int cj = j*256 + tid;
    int r  = cj >> 3;
    int sw = ((cj & 7) ^ (r & 7)) * 8;
    int rm = m0 + r; if (rm > c-1) rm = c-1;
    asrc[j] = xbf + (size_t)rows[off_e + rm]*HD + sw;
  }

  // B fp32 staging: thread -> row br = tid>>2, 16-float group bq = tid&3
  const int br = tid >> 2;
  const int bq = tid & 3;
  const float* bgbase = gw + ((size_t)e*FF + n0 + br)*HD + bq*16;
  const float* bubase = uw + ((size_t)e*FF + n0 + br)*HD + bq*16;
  unsigned short* bgdst0 = &Bg[br*64 + (((bq*2    ) ^ (br & 7))*8)];
  unsigned short* bgdst1 = &Bg[br*64 + (((bq*2 + 1) ^ (br & 7))*8)];
  unsigned short* budst0 = &Bu[br*64 + (((bq*2    ) ^ (br & 7))*8)];
  unsigned short* budst1 = &Bu[br*64 + (((bq*2 + 1) ^ (br & 7))*8)];

  f32x4 accg[4][2] = {};
  f32x4 accu[4][2] = {};

  for (int ks = 0; ks < HD/64; ++ks){
    // issue fp32 B loads early (latency hides under previous MFMA phase)
    const float4* gp = (const float4*)(bgbase + ks*64);
    const float4* up = (const float4*)(bubase + ks*64);
    float4 g0 = gp[0], g1 = gp[1], g2 = gp[2], g3 = gp[3];
    float4 u0 = up[0], u1 = up[1], u2 = up[2], u3 = up[3];
    #pragma unroll
    for (int j = 0; j < 4; ++j)
      gload16(asrc[j] + ks*64, &As[(j*256+tid)*8]);
    *(u16x8*)bgdst0 = pack8(g0, g1);
    *(u16x8*)bgdst1 = pack8(g2, g3);
    *(u16x8*)budst0 = pack8(u0, u1);
    *(u16x8*)budst1 = pack8(u2, u3);
    __syncthreads();
    #pragma unroll
    for (int kk = 0; kk < 2; ++kk){
      bf16x8 a[4], fg[2], fu[2];
      #pragma unroll
      for (int m = 0; m < 4; ++m){
        int r = wm*64 + m*16 + ar;
        a[m] = *(const bf16x8*)&As[r*64 + (((kk*4 + kb) ^ (r & 7))*8)];
      }
      #pragma unroll
      for (int n = 0; n < 2; ++n){
        int rf = wn*32 + n*16 + ar;
        int o  = rf*64 + (((kk*4 + kb) ^ (rf & 7))*8);
        fg[n] = *(const bf16x8*)&Bg[o];
        fu[n] = *(const bf16x8*)&Bu[o];
      }
      #pragma unroll
      for (int m = 0; m < 4; ++m){
        #pragma unroll
        for (int n = 0; n < 2; ++n){
          accg[m][n] = __builtin_amdgcn_mfma_f32_16x16x32_bf16(a[m], fg[n], accg[m][n], 0, 0, 0);
          accu[m][n] = __builtin_amdgcn_mfma_f32_16x16x32_bf16(a[m], fu[n], accu[m][n], 0, 0, 0);
        }
      }
    }
    __syncthreads();
  }

  #pragma unroll
  for (int m = 0; m < 4; ++m){
    #pragma unroll
    for (int n = 0; n < 2; ++n){
      int fcol = n0 + wn*32 + n*16 + ar;
      #pragma unroll
      for (int i = 0; i < 4; ++i){
        int gr = m0 + wm*64 + m*16 + kb*4 + i;
        if (gr < c){
          float g = accg[m][n][i];
          float u = accu[m][n][i];
          float s = g / (1.0f + expf(-g));
          hbuf[(size_t)(off_e + gr)*FF + fcol] = f2bf(s * u);
        }
      }
    }
  }
}

// ---------------- stage-2: y = h @ downT, grouped ----------------
// BM=128 x BN=128, BK=64. A (bf16 hbuf) via global_load_lds; B (fp32 down
// weights) via reg-staging cvt, swizzled ds_write.
__global__ __launch_bounds__(256, 3) void gemm_down(
    const unsigned short* __restrict__ hbuf,
    const float* __restrict__ dw,
    const int* __restrict__ cnt, const int* __restrict__ offs,
    unsigned short* __restrict__ ybuf)
{
  const int cpx = gridDim.x >> 3;
  const int bid = blockIdx.x;
  const int nid = (bid & 7) * cpx + (bid >> 3);
  const int mb   = nid & 31;
  const int rest = nid >> 5;
  const int nb   = rest & 7;
  const int e    = rest >> 3;

  const int c  = cnt[e];
  const int m0 = mb * 128;
  if (m0 >= c) return;
  const int n0 = nb * 128;
  const int off_e = offs[e];

  __shared__ unsigned short As[128*64];
  __shared__ unsigned short Bs[128*64];

  const int tid  = threadIdx.x;
  const int lane = tid & 63;
  const int wid  = tid >> 6;
  const int ar = lane & 15;
  const int kb = lane >> 4;
  const int wm = wid >> 1;
  const int wn = wid & 1;

  const unsigned short* asrc[4];
  #pragma unroll
  for (int j = 0; j < 4; ++j){
    int cj = j*256 + tid;
    int r  = cj >> 3;
    int sw = ((cj & 7) ^ (r & 7)) * 8;
    int rm = m0 + r; if (rm > c-1) rm = c-1;
    asrc[j] = hbuf + (size_t)(off_e + rm)*FF + sw;
  }

  // B fp32 staging: row br = tid>>1 (0..127), half bq = tid&1 (32 floats each)
  const int br = tid >> 1;
  const int bq = tid & 1;
  const float* bbase = dw + ((size_t)e*HD + n0 + br)*FF + bq*32;
  unsigned short* bdst[4];
  #pragma unroll
  for (int j = 0; j < 4; ++j)
    bdst[j] = &Bs[br*64 + (((bq*4 + j) ^ (br & 7))*8)];

  f32x4 acc[4][4] = {};

  for (int ks = 0; ks < FF/64; ++ks){
    const float4* bp = (const float4*)(bbase + ks*64);
    float4 b0 = bp[0], b1 = bp[1], b2 = bp[2], b3 = bp[3];
    float4 b4 = bp[4], b5 = bp[5], b6 = bp[6], b7 = bp[7];
    #pragma unroll
    for (int j = 0; j < 4; ++j)
      gload16(asrc[j] + ks*64, &As[(j*256+tid)*8]);
    *(u16x8*)bdst[0] = pack8(b0, b1);
    *(u16x8*)bdst[1] = pack8(b2, b3);
    *(u16x8*)bdst[2] = pack8(b4, b5);
    *(u16x8*)bdst[3] = pack8(b6, b7);
    __syncthreads();
    #pragma unroll
    for (int kk = 0; kk < 2; ++kk){
      bf16x8 a[4], b[4];
      #pragma unroll
      for (int m = 0; m < 4; ++m){
        int r = wm*64 + m*16 + ar;
        a[m] = *(const bf16x8*)&As[r*64 + (((kk*4 + kb) ^ (r & 7))*8)];
      }
      #pragma unroll
      for (int n = 0; n < 4; ++n){
        int r = wn*64 + n*16 + ar;
        b[n] = *(const bf16x8*)&Bs[r*64 + (((kk*4 + kb) ^ (r & 7))*8)];
      }
      #pragma unroll
      for (int m = 0; m < 4; ++m){
        #pragma unroll
        for (int n = 0; n < 4; ++n){
          acc[m][n] = __builtin_amdgcn_mfma_f32_16x16x32_bf16(a[m], b[n], acc[m][n], 0, 0, 0);
        }
      }
    }
    __syncthreads();
  }

  #pragma unroll
  for (int m = 0; m < 4; ++m){
    #pragma unroll
    for (int n = 0; n < 4; ++n){
      int col = n0 + wn*64 + n*16 + ar;
      #pragma unroll
      for (int i = 0; i < 4; ++i){
        int gr = m0 + wm*64 + m*16 + kb*4 + i;
        if (gr < c){
          ybuf[(size_t)(off_e + gr)*HD + col] = f2bf(acc[m][n][i]);
        }
      }
    }
  }
}

// ---------------- combine ----------------
__global__ __launch_bounds__(256) void combine_kernel(
    const unsigned short* __restrict__ ybuf,
    const int* __restrict__ slot_of, const float* __restrict__ topk_w,
    float* __restrict__ out)
{
  const int t   = blockIdx.x;
  const int tid = threadIdx.x;
  const int c0  = tid * 4;
  float4 acc = {0.f, 0.f, 0.f, 0.f};
  #pragma unroll
  for (int k = 0; k < TOPK; ++k){
    int slot = slot_of[t*TOPK + k];
    float w  = topk_w[t*TOPK + k];
    ushort4 v = *(const ushort4*)&ybuf[(size_t)slot*HD + c0];
    acc.x += w * bf2f(v.x);
    acc.y += w * bf2f(v.y);
    acc.z += w * bf2f(v.z);
    acc.w += w * bf2f(v.w);
  }
  ((float4*)out)[(size_t)t*(HD/4) + tid] = acc;
}

extern "C" void kernel_launch(void* const* d_in, const int* in_sizes, int n_in,
                              void* d_out, int out_size, void* d_ws, size_t ws_size,
                              hipStream_t stream)
{
  const float* x  = (const float*)d_in[0];
  const float* rw = (const float*)d_in[1];
  const float* gw = (const float*)d_in[2];
  const float* uw = (const float*)d_in[3];
  const float* dw = (const float*)d_in[4];
  float* out = (float*)d_out;

  char* ws = (char*)d_ws;
  size_t off = 0;
  auto alloc = [&](size_t b) -> void* {
    void* p = ws + off;
    off += (b + 255) & ~(size_t)255;
    return p;
  };

  unsigned short* xbf  = (unsigned short*)alloc((size_t)T_TOK*HD*2);
  unsigned short* hbuf = (unsigned short*)alloc((size_t)NPAIR*FF*2);
  unsigned short* ybuf = (unsigned short*)alloc((size_t)NPAIR*HD*2);
  int*   tki   = (int*)alloc((size_t)T_TOK*TOPK*4);
  float* tkw   = (float*)alloc((size_t)T_TOK*TOPK*4);
  int*   rowsb = (int*)alloc((size_t)NPAIR*4);
  int*   slotf = (int*)alloc((size_t)NPAIR*4);
  int*   cntb  = (int*)alloc(NE*4);
  int*   offsb = (int*)alloc(NE*4);

  router_kernel<<<T_TOK, 256, 0, stream>>>(x, rw, xbf, tki, tkw);
  lists_kernel<<<NE, 256, 0, stream>>>(tki, rowsb, slotf, cntb, offsb);

  gemm_gateup<<<32*(FF/64)*NE, 256, 0, stream>>>(xbf, gw, uw, rowsb, cntb, offsb, hbuf);
  gemm_down<<<32*(HD/128)*NE, 256, 0, stream>>>(hbuf, dw, cntb, offsb, ybuf);

  combine_kernel<<<T_TOK, 256, 0, stream>>>(ybuf, slotf, tkw, out);
}

// Round 7
// 860.953 us; speedup vs baseline: 1.7695x; 1.7695x over previous
//
#include <hip/hip_runtime.h>
#include <hip/hip_bf16.h>
#include <stdint.h>
#include <math.h>

#define T_TOK 4096
#define HD    1024
#define NE    16
#define FF    2816
#define TOPK  8
#define NPAIR (T_TOK*TOPK)

typedef __attribute__((ext_vector_type(8))) __bf16 bf16x8;
typedef __attribute__((ext_vector_type(4))) float  f32x4;

__device__ __forceinline__ unsigned short f2bf(float x){
  union { float f; unsigned u; } c; c.f = x;
  unsigned r = (c.u + 0x7FFFu + ((c.u >> 16) & 1u)) >> 16;
  return (unsigned short)r;
}
__device__ __forceinline__ float bf2f(unsigned short h){
  union { unsigned u; float f; } c; c.u = ((unsigned)h) << 16; return c.f;
}

// async global->LDS, 16B per lane
__device__ __forceinline__ void gload16(const void* src, void* lds_dst){
  __builtin_amdgcn_global_load_lds((const __attribute__((address_space(1))) unsigned int*)src,
                                   (__attribute__((address_space(3))) unsigned int*)lds_dst,
                                   16, 0, 0);
}

// ---------------- fused fp32 -> bf16 (RNE) conversion of all 3 weight tensors ----------------
__global__ __launch_bounds__(256) void convert3_kernel(
    const float* __restrict__ g, const float* __restrict__ u, const float* __restrict__ d,
    unsigned short* __restrict__ gb, unsigned short* __restrict__ ub, unsigned short* __restrict__ db,
    int n4each)
{
  int i = blockIdx.x * blockDim.x + threadIdx.x;
  int stride = gridDim.x * blockDim.x;
  int total = 3 * n4each;
  for (; i < total; i += stride){
    const float* s; unsigned short* dst; int j;
    if (i < n4each){ s = g; dst = gb; j = i; }
    else if (i < 2*n4each){ s = u; dst = ub; j = i - n4each; }
    else { s = d; dst = db; j = i - 2*n4each; }
    float4 v = ((const float4*)s)[j];
    ushort4 o;
    o.x = f2bf(v.x); o.y = f2bf(v.y); o.z = f2bf(v.z); o.w = f2bf(v.w);
    ((ushort4*)dst)[j] = o;
  }
}

// ---------------- router ----------------
__global__ __launch_bounds__(256) void router_kernel(
    const float* __restrict__ x, const float* __restrict__ rw,
    unsigned short* __restrict__ xbf, int* __restrict__ topk_idx, float* __restrict__ topk_w)
{
  __shared__ float xs[HD];
  __shared__ float lg[NE];
  const int t   = blockIdx.x;
  const int tid = threadIdx.x;
  const int lane = tid & 63;
  const int wid  = tid >> 6;

  float4 v = ((const float4*)(x + (size_t)t*HD))[tid];
  ((float4*)xs)[tid] = v;
  ushort4 o;
  o.x = f2bf(v.x); o.y = f2bf(v.y); o.z = f2bf(v.z); o.w = f2bf(v.w);
  ((ushort4*)(xbf + (size_t)t*HD))[tid] = o;
  __syncthreads();

  for (int ee = 0; ee < 4; ++ee){
    int e = wid*4 + ee;
    const float* w = rw + (size_t)e*HD;
    float p = 0.f;
    for (int j = lane; j < HD; j += 64) p += xs[j] * w[j];
    #pragma unroll
    for (int offs = 32; offs; offs >>= 1) p += __shfl_xor(p, offs, 64);
    if (lane == 0) lg[e] = p;
  }
  __syncthreads();

  if (tid == 0){
    float vals[NE];
    #pragma unroll
    for (int e = 0; e < NE; ++e) vals[e] = lg[e];
    int   idx[TOPK]; float tv[TOPK];
    for (int k = 0; k < TOPK; ++k){
      int bi = 0; float bv = -3.4e38f;
      for (int e = 0; e < NE; ++e) if (vals[e] > bv){ bv = vals[e]; bi = e; }
      idx[k] = bi; tv[k] = bv; vals[bi] = -3.4e38f;
    }
    float m = tv[0];
    float ex[TOPK]; float s = 0.f;
    for (int k = 0; k < TOPK; ++k){ ex[k] = expf(tv[k] - m); s += ex[k]; }
    float inv = 1.f / s;
    for (int k = 0; k < TOPK; ++k){
      topk_idx[t*TOPK + k] = idx[k];
      topk_w [t*TOPK + k] = ex[k] * inv;
    }
  }
}

// ---------------- deterministic token lists (derives cnt+offs itself) ----------------
__global__ __launch_bounds__(256) void lists_kernel(
    const int* __restrict__ topk_idx,
    int* __restrict__ rows, int* __restrict__ slot_of,
    int* __restrict__ cnt, int* __restrict__ offs_out)
{
  const int e = blockIdx.x;
  const int tid = threadIdx.x;
  const int lane = tid & 63;
  const int wid  = tid >> 6;

  __shared__ int wred[4];
  __shared__ int wred2[4];
  __shared__ int soff;

  int nlt = 0, ceq = 0;
  for (int t = tid; t < T_TOK; t += 256){
    #pragma unroll
    for (int k = 0; k < TOPK; ++k){
      int vv = topk_idx[t*TOPK + k];
      nlt += (vv < e) ? 1 : 0;
      ceq += (vv == e) ? 1 : 0;
    }
  }
  #pragma unroll
  for (int offs = 32; offs; offs >>= 1){
    nlt += __shfl_xor(nlt, offs, 64);
    ceq += __shfl_xor(ceq, offs, 64);
  }
  if (lane == 0){ wred[wid] = nlt; wred2[wid] = ceq; }
  __syncthreads();
  if (tid == 0){
    int off = wred[0] + wred[1] + wred[2] + wred[3];
    int c   = wred2[0] + wred2[1] + wred2[2] + wred2[3];
    offs_out[e] = off;
    cnt[e] = c;
    soff = off;
  }
  __syncthreads();
  const int off = soff;

  __shared__ int wc[4];
  int base = 0;
  for (int c0 = 0; c0 < T_TOK; c0 += 256){
    int t = c0 + tid;
    int kpos = -1;
    #pragma unroll
    for (int k = 0; k < TOPK; ++k) if (topk_idx[t*TOPK + k] == e) kpos = k;
    bool f = (kpos >= 0);
    unsigned long long m = __ballot(f);
    if (lane == 0) wc[wid] = __popcll(m);
    __syncthreads();
    int p = base;
    for (int w = 0; w < wid; ++w) p += wc[w];
    p += __popcll(m & ((1ULL << lane) - 1ULL));
    if (f){
      rows[off + p] = t;
      slot_of[t*TOPK + kpos] = off + p;
    }
    int tot = wc[0] + wc[1] + wc[2] + wc[3];
    __syncthreads();
    base += tot;
  }
}

// ---------------- stage-1: h = silu(x@gateT) * (x@upT), grouped ----------------
// BM=128 (tokens) x BF=64, BK=64, 4 waves (2Mx2F, wave 64x32 each for g and u),
// single-buffered LDS (32KB, 3+ blocks/CU), m97-style 2-barrier loop,
// XOR-swizzled LDS rows (bank-conflict-free ds_read_b128).
__global__ __launch_bounds__(256, 3) void gemm_gateup(
    const unsigned short* __restrict__ xbf,
    const unsigned short* __restrict__ gw,
    const unsigned short* __restrict__ uw,
    const int* __restrict__ rows, const int* __restrict__ cnt, const int* __restrict__ offs,
    unsigned short* __restrict__ hbuf)
{
  // 1D grid = 32 * (FF/64) * NE, bijective XCD swizzle (grid % 8 == 0)
  const int cpx = gridDim.x >> 3;
  const int bid = blockIdx.x;
  const int nid = (bid & 7) * cpx + (bid >> 3);
  const int mb   = nid & 31;
  const int rest = nid >> 5;
  const int nb   = rest % (FF/64);
  const int e    = rest / (FF/64);

  const int c  = cnt[e];
  const int m0 = mb * 128;
  if (m0 >= c) return;
  const int n0 = nb * 64;
  const int off_e = offs[e];

  __shared__ unsigned short As[128*64];
  __shared__ unsigned short Bg[64*64];
  __shared__ unsigned short Bu[64*64];

  const int tid  = threadIdx.x;
  const int lane = tid & 63;
  const int wid  = tid >> 6;
  const int ar = lane & 15;
  const int kb = lane >> 4;
  const int wm = wid >> 1;
  const int wn = wid & 1;

  // chunk c = j*256+tid -> row c>>3, phys slot c&7; phys slot holds logical (c&7)^(row&7)
  const unsigned short* asrc[4];
  #pragma unroll
  for (int j = 0; j < 4; ++j){
    int cj = j*256 + tid;
    int r  = cj >> 3;
    int sw = ((cj & 7) ^ (r & 7)) * 8;
    int rm = m0 + r; if (rm > c-1) rm = c-1;
    asrc[j] = xbf + (size_t)rows[off_e + rm]*HD + sw;
  }
  const unsigned short* bgsrc[2];
  const unsigned short* busrc[2];
  #pragma unroll
  for (int j = 0; j < 2; ++j){
    int cj = j*256 + tid;
    int r  = cj >> 3;
    int sw = ((cj & 7) ^ (r & 7)) * 8;
    bgsrc[j] = gw + ((size_t)e*FF + n0 + r)*HD + sw;
    busrc[j] = uw + ((size_t)e*FF + n0 + r)*HD + sw;
  }

  f32x4 accg[4][2] = {};
  f32x4 accu[4][2] = {};

  for (int ks = 0; ks < HD/64; ++ks){
    #pragma unroll
    for (int j = 0; j < 4; ++j)
      gload16(asrc[j] + ks*64, &As[(j*256+tid)*8]);
    #pragma unroll
    for (int j = 0; j < 2; ++j){
      gload16(bgsrc[j] + ks*64, &Bg[(j*256+tid)*8]);
      gload16(busrc[j] + ks*64, &Bu[(j*256+tid)*8]);
    }
    __syncthreads();
    #pragma unroll
    for (int kk = 0; kk < 2; ++kk){
      bf16x8 a[4], fg[2], fu[2];
      #pragma unroll
      for (int m = 0; m < 4; ++m){
        int r = wm*64 + m*16 + ar;
        a[m] = *(const bf16x8*)&As[r*64 + (((kk*4 + kb) ^ (r & 7))*8)];
      }
      #pragma unroll
      for (int n = 0; n < 2; ++n){
        int rf = wn*32 + n*16 + ar;
        int o  = rf*64 + (((kk*4 + kb) ^ (rf & 7))*8);
        fg[n] = *(const bf16x8*)&Bg[o];
        fu[n] = *(const bf16x8*)&Bu[o];
      }
      #pragma unroll
      for (int m = 0; m < 4; ++m){
        #pragma unroll
        for (int n = 0; n < 2; ++n){
          accg[m][n] = __builtin_amdgcn_mfma_f32_16x16x32_bf16(a[m], fg[n], accg[m][n], 0, 0, 0);
          accu[m][n] = __builtin_amdgcn_mfma_f32_16x16x32_bf16(a[m], fu[n], accu[m][n], 0, 0, 0);
        }
      }
    }
    __syncthreads();
  }

  #pragma unroll
  for (int m = 0; m < 4; ++m){
    #pragma unroll
    for (int n = 0; n < 2; ++n){
      int fcol = n0 + wn*32 + n*16 + ar;
      #pragma unroll
      for (int i = 0; i < 4; ++i){
        int gr = m0 + wm*64 + m*16 + kb*4 + i;
        if (gr < c){
          float g = accg[m][n][i];
          float u = accu[m][n][i];
          float s = g / (1.0f + expf(-g));
          hbuf[(size_t)(off_e + gr)*FF + fcol] = f2bf(s * u);
        }
      }
    }
  }
}

// ---------------- stage-2: y = h @ downT, grouped ----------------
// BM=128 x BN=128, BK=64, 4 waves (2x2, wave 64x64), same structure.
__global__ __launch_bounds__(256, 3) void gemm_down(
    const unsigned short* __restrict__ hbuf,
    const unsigned short* __restrict__ dw,
    const int* __restrict__ cnt, const int* __restrict__ offs,
    unsigned short* __restrict__ ybuf)
{
  // 1D grid = 32 * (HD/128) * NE = 4096, XCD swizzle
  const int cpx = gridDim.x >> 3;
  const int bid = blockIdx.x;
  const int nid = (bid & 7) * cpx + (bid >> 3);
  const int mb   = nid & 31;
  const int rest = nid >> 5;
  const int nb   = rest & 7;
  const int e    = rest >> 3;

  const int c  = cnt[e];
  const int m0 = mb * 128;
  if (m0 >= c) return;
  const int n0 = nb * 128;
  const int off_e = offs[e];

  __shared__ unsigned short As[128*64];
  __shared__ unsigned short Bs[128*64];

  const int tid  = threadIdx.x;
  const int lane = tid & 63;
  const int wid  = tid >> 6;
  const int ar = lane & 15;
  const int kb = lane >> 4;
  const int wm = wid >> 1;
  const int wn = wid & 1;

  const unsigned short* asrc[4];
  const unsigned short* bsrc[4];
  #pragma unroll
  for (int j = 0; j < 4; ++j){
    int cj = j*256 + tid;
    int r  = cj >> 3;
    int sw = ((cj & 7) ^ (r & 7)) * 8;
    int rm = m0 + r; if (rm > c-1) rm = c-1;
    asrc[j] = hbuf + (size_t)(off_e + rm)*FF + sw;
    bsrc[j] = dw + ((size_t)e*HD + n0 + r)*FF + sw;
  }

  f32x4 acc[4][4] = {};

  for (int ks = 0; ks < FF/64; ++ks){
    #pragma unroll
    for (int j = 0; j < 4; ++j){
      gload16(asrc[j] + ks*64, &As[(j*256+tid)*8]);
      gload16(bsrc[j] + ks*64, &Bs[(j*256+tid)*8]);
    }
    __syncthreads();
    #pragma unroll
    for (int kk = 0; kk < 2; ++kk){
      bf16x8 a[4], b[4];
      #pragma unroll
      for (int m = 0; m < 4; ++m){
        int r = wm*64 + m*16 + ar;
        a[m] = *(const bf16x8*)&As[r*64 + (((kk*4 + kb) ^ (r & 7))*8)];
      }
      #pragma unroll
      for (int n = 0; n < 4; ++n){
        int r = wn*64 + n*16 + ar;
        b[n] = *(const bf16x8*)&Bs[r*64 + (((kk*4 + kb) ^ (r & 7))*8)];
      }
      #pragma unroll
      for (int m = 0; m < 4; ++m){
        #pragma unroll
        for (int n = 0; n < 4; ++n){
          acc[m][n] = __builtin_amdgcn_mfma_f32_16x16x32_bf16(a[m], b[n], acc[m][n], 0, 0, 0);
        }
      }
    }
    __syncthreads();
  }

  #pragma unroll
  for (int m = 0; m < 4; ++m){
    #pragma unroll
    for (int n = 0; n < 4; ++n){
      int col = n0 + wn*64 + n*16 + ar;
      #pragma unroll
      for (int i = 0; i < 4; ++i){
        int gr = m0 + wm*64 + m*16 + kb*4 + i;
        if (gr < c){
          ybuf[(size_t)(off_e + gr)*HD + col] = f2bf(acc[m][n][i]);
        }
      }
    }
  }
}

// ---------------- combine ----------------
__global__ __launch_bounds__(256) void combine_kernel(
    const unsigned short* __restrict__ ybuf,
    const int* __restrict__ slot_of, const float* __restrict__ topk_w,
    float* __restrict__ out)
{
  const int t   = blockIdx.x;
  const int tid = threadIdx.x;
  const int c0  = tid * 4;
  float4 acc = {0.f, 0.f, 0.f, 0.f};
  #pragma unroll
  for (int k = 0; k < TOPK; ++k){
    int slot = slot_of[t*TOPK + k];
    float w  = topk_w[t*TOPK + k];
    ushort4 v = *(const ushort4*)&ybuf[(size_t)slot*HD + c0];
    acc.x += w * bf2f(v.x);
    acc.y += w * bf2f(v.y);
    acc.z += w * bf2f(v.z);
    acc.w += w * bf2f(v.w);
  }
  ((float4*)out)[(size_t)t*(HD/4) + tid] = acc;
}

extern "C" void kernel_launch(void* const* d_in, const int* in_sizes, int n_in,
                              void* d_out, int out_size, void* d_ws, size_t ws_size,
                              hipStream_t stream)
{
  const float* x  = (const float*)d_in[0];
  const float* rw = (const float*)d_in[1];
  const float* gw = (const float*)d_in[2];
  const float* uw = (const float*)d_in[3];
  const float* dw = (const float*)d_in[4];
  float* out = (float*)d_out;

  char* ws = (char*)d_ws;
  size_t off = 0;
  auto alloc = [&](size_t b) -> void* {
    void* p = ws + off;
    off += (b + 255) & ~(size_t)255;
    return p;
  };

  unsigned short* gwb  = (unsigned short*)alloc((size_t)NE*FF*HD*2);
  unsigned short* uwb  = (unsigned short*)alloc((size_t)NE*FF*HD*2);
  unsigned short* dwb  = (unsigned short*)alloc((size_t)NE*HD*FF*2);
  unsigned short* xbf  = (unsigned short*)alloc((size_t)T_TOK*HD*2);
  unsigned short* hbuf = (unsigned short*)alloc((size_t)NPAIR*FF*2);
  unsigned short* ybuf = (unsigned short*)alloc((size_t)NPAIR*HD*2);
  int*   tki   = (int*)alloc((size_t)T_TOK*TOPK*4);
  float* tkw   = (float*)alloc((size_t)T_TOK*TOPK*4);
  int*   rowsb = (int*)alloc((size_t)NPAIR*4);
  int*   slotf = (int*)alloc((size_t)NPAIR*4);
  int*   cntb  = (int*)alloc(NE*4);
  int*   offsb = (int*)alloc(NE*4);

  const int n4 = NE*FF*HD/4;
  convert3_kernel<<<4096, 256, 0, stream>>>(gw, uw, dw, gwb, uwb, dwb, n4);

  router_kernel<<<T_TOK, 256, 0, stream>>>(x, rw, xbf, tki, tkw);
  lists_kernel<<<NE, 256, 0, stream>>>(tki, rowsb, slotf, cntb, offsb);

  gemm_gateup<<<32*(FF/64)*NE, 256, 0, stream>>>(xbf, gwb, uwb, rowsb, cntb, offsb, hbuf);
  gemm_down<<<32*(HD/128)*NE, 256, 0, stream>>>(hbuf, dwb, cntb, offsb, ybuf);

  combine_kernel<<<T_TOK, 256, 0, stream>>>(ybuf, slotf, tkw, out);
}

// Round 8
// 824.369 us; speedup vs baseline: 1.8480x; 1.0444x over previous
//
#include <hip/hip_runtime.h>
#include <hip/hip_bf16.h>
#include <stdint.h>
#include <math.h>

#define T_TOK 4096
#define HD    1024
#define NE    16
#define FF    2816
#define TOPK  8
#define NPAIR (T_TOK*TOPK)

typedef __attribute__((ext_vector_type(8))) __bf16 bf16x8;
typedef __attribute__((ext_vector_type(4))) float  f32x4;

__device__ __forceinline__ unsigned short f2bf(float x){
  union { float f; unsigned u; } c; c.f = x;
  unsigned r = (c.u + 0x7FFFu + ((c.u >> 16) & 1u)) >> 16;
  return (unsigned short)r;
}
__device__ __forceinline__ float bf2f(unsigned short h){
  union { unsigned u; float f; } c; c.u = ((unsigned)h) << 16; return c.f;
}

// async global->LDS, 16B per lane
__device__ __forceinline__ void gload16(const void* src, void* lds_dst){
  __builtin_amdgcn_global_load_lds((const __attribute__((address_space(1))) unsigned int*)src,
                                   (__attribute__((address_space(3))) unsigned int*)lds_dst,
                                   16, 0, 0);
}

// ---------------- fused: convert gate+up (fp32->bf16 RNE) + router ----------------
// bid even -> convert chunk; bid odd -> router for token t = bid>>1.
__global__ __launch_bounds__(256) void convgu_router_kernel(
    const float* __restrict__ g, const float* __restrict__ u,
    unsigned short* __restrict__ gb, unsigned short* __restrict__ ub,
    const float* __restrict__ x, const float* __restrict__ rw,
    unsigned short* __restrict__ xbf, int* __restrict__ topk_idx, float* __restrict__ topk_w)
{
  __shared__ float xs[HD];
  __shared__ float lg[NE];
  const int tid = threadIdx.x;

  if ((blockIdx.x & 1) == 0){
    // ---- convert role: gate then up, flat over 2*n4 float4 chunks ----
    const int n4 = NE*FF*HD/4;           // 11,534,336 per tensor
    const int cid = blockIdx.x >> 1;     // 0..4095
    int i = cid*256 + tid;
    const int stride = 4096*256;
    const int total = 2*n4;
    for (; i < total; i += stride){
      const float* s; unsigned short* dst; int j;
      if (i < n4){ s = g; dst = gb; j = i; }
      else { s = u; dst = ub; j = i - n4; }
      float4 v = ((const float4*)s)[j];
      ushort4 o;
      o.x = f2bf(v.x); o.y = f2bf(v.y); o.z = f2bf(v.z); o.w = f2bf(v.w);
      ((ushort4*)dst)[j] = o;
    }
    return;
  }

  // ---- router role ----
  const int t   = blockIdx.x >> 1;
  const int lane = tid & 63;
  const int wid  = tid >> 6;

  float4 v = ((const float4*)(x + (size_t)t*HD))[tid];
  ((float4*)xs)[tid] = v;
  ushort4 o;
  o.x = f2bf(v.x); o.y = f2bf(v.y); o.z = f2bf(v.z); o.w = f2bf(v.w);
  ((ushort4*)(xbf + (size_t)t*HD))[tid] = o;
  __syncthreads();

  for (int ee = 0; ee < 4; ++ee){
    int e = wid*4 + ee;
    const float* w = rw + (size_t)e*HD;
    float p = 0.f;
    for (int j = lane; j < HD; j += 64) p += xs[j] * w[j];
    #pragma unroll
    for (int offs = 32; offs; offs >>= 1) p += __shfl_xor(p, offs, 64);
    if (lane == 0) lg[e] = p;
  }
  __syncthreads();

  if (tid == 0){
    float vals[NE];
    #pragma unroll
    for (int e = 0; e < NE; ++e) vals[e] = lg[e];
    int   idx[TOPK]; float tv[TOPK];
    for (int k = 0; k < TOPK; ++k){
      int bi = 0; float bv = -3.4e38f;
      for (int e = 0; e < NE; ++e) if (vals[e] > bv){ bv = vals[e]; bi = e; }
      idx[k] = bi; tv[k] = bv; vals[bi] = -3.4e38f;
    }
    float m = tv[0];
    float ex[TOPK]; float s = 0.f;
    for (int k = 0; k < TOPK; ++k){ ex[k] = expf(tv[k] - m); s += ex[k]; }
    float inv = 1.f / s;
    for (int k = 0; k < TOPK; ++k){
      topk_idx[t*TOPK + k] = idx[k];
      topk_w [t*TOPK + k] = ex[k] * inv;
    }
  }
}

// ---------------- deterministic token lists (derives cnt+offs itself) ----------------
__global__ __launch_bounds__(256) void lists_kernel(
    const int* __restrict__ topk_idx,
    int* __restrict__ rows, int* __restrict__ slot_of,
    int* __restrict__ cnt, int* __restrict__ offs_out)
{
  const int e = blockIdx.x;
  const int tid = threadIdx.x;
  const int lane = tid & 63;
  const int wid  = tid >> 6;

  __shared__ int wred[4];
  __shared__ int wred2[4];
  __shared__ int soff;

  int nlt = 0, ceq = 0;
  for (int t = tid; t < T_TOK; t += 256){
    #pragma unroll
    for (int k = 0; k < TOPK; ++k){
      int vv = topk_idx[t*TOPK + k];
      nlt += (vv < e) ? 1 : 0;
      ceq += (vv == e) ? 1 : 0;
    }
  }
  #pragma unroll
  for (int offs = 32; offs; offs >>= 1){
    nlt += __shfl_xor(nlt, offs, 64);
    ceq += __shfl_xor(ceq, offs, 64);
  }
  if (lane == 0){ wred[wid] = nlt; wred2[wid] = ceq; }
  __syncthreads();
  if (tid == 0){
    int off = wred[0] + wred[1] + wred[2] + wred[3];
    int c   = wred2[0] + wred2[1] + wred2[2] + wred2[3];
    offs_out[e] = off;
    cnt[e] = c;
    soff = off;
  }
  __syncthreads();
  const int off = soff;

  __shared__ int wc[4];
  int base = 0;
  for (int c0 = 0; c0 < T_TOK; c0 += 256){
    int t = c0 + tid;
    int kpos = -1;
    #pragma unroll
    for (int k = 0; k < TOPK; ++k) if (topk_idx[t*TOPK + k] == e) kpos = k;
    bool f = (kpos >= 0);
    unsigned long long m = __ballot(f);
    if (lane == 0) wc[wid] = __popcll(m);
    __syncthreads();
    int p = base;
    for (int w = 0; w < wid; ++w) p += wc[w];
    p += __popcll(m & ((1ULL << lane) - 1ULL));
    if (f){
      rows[off + p] = t;
      slot_of[t*TOPK + kpos] = off + p;
    }
    int tot = wc[0] + wc[1] + wc[2] + wc[3];
    __syncthreads();
    base += tot;
  }
}

// ---------------- stage-1: h = silu(x@gateT) * (x@upT), grouped ----------------
// BM=128 x BF=64, BK=64, 4 waves, m97-style 2-barrier loop, XOR-swizzled LDS.
// Grid 24576 = 22528 GEMM blocks + 2048 convert-role blocks (every 12th swizzled
// nid) which convert down_w fp32->bf16, riding the spare HBM BW under the
// compute-bound GEMM. Per XCD: 3072 nids -> 2816 GEMM + 256 convert (balanced).
__global__ __launch_bounds__(256, 3) void gemm_gateup(
    const unsigned short* __restrict__ xbf,
    const unsigned short* __restrict__ gw,
    const unsigned short* __restrict__ uw,
    const int* __restrict__ rows, const int* __restrict__ cnt, const int* __restrict__ offs,
    unsigned short* __restrict__ hbuf,
    const float* __restrict__ dwf, unsigned short* __restrict__ dwb)
{
  const int cpx = gridDim.x >> 3;
  const int bid = blockIdx.x;
  const int nid = (bid & 7) * cpx + (bid >> 3);
  const int q  = nid / 12;
  const int rr = nid - q*12;

  if (rr == 11){
    // ---- convert role: down_w fp32 -> bf16 ----
    const int n4 = NE*HD*FF/4;   // 2,883,584 float4
    int i = q*256 + threadIdx.x;
    const int stride = 2048*256;
    for (; i < n4; i += stride){
      float4 v = ((const float4*)dwf)[i];
      ushort4 o;
      o.x = f2bf(v.x); o.y = f2bf(v.y); o.z = f2bf(v.z); o.w = f2bf(v.w);
      ((ushort4*)dwb)[i] = o;
    }
    return;
  }
  const int gid = q*11 + rr;           // 0..22527
  const int mb   = gid & 31;
  const int rest = gid >> 5;
  const int nb   = rest % (FF/64);
  const int e    = rest / (FF/64);

  const int c  = cnt[e];
  const int m0 = mb * 128;
  if (m0 >= c) return;
  const int n0 = nb * 64;
  const int off_e = offs[e];

  __shared__ unsigned short As[128*64];
  __shared__ unsigned short Bg[64*64];
  __shared__ unsigned short Bu[64*64];

  const int tid  = threadIdx.x;
  const int lane = tid & 63;
  const int wid  = tid >> 6;
  const int ar = lane & 15;
  const int kb = lane >> 4;
  const int wm = wid >> 1;
  const int wn = wid & 1;

  // chunk cj = j*256+tid -> row cj>>3, phys slot cj&7 holds logical (cj&7)^(row&7)
  const unsigned short* asrc[4];
  #pragma unroll
  for (int j = 0; j < 4; ++j){
    int cj = j*256 + tid;
    int r  = cj >> 3;
    int sw = ((cj & 7) ^ (r & 7)) * 8;
    int rm = m0 + r; if (rm > c-1) rm = c-1;
    asrc[j] = xbf + (size_t)rows[off_e + rm]*HD + sw;
  }
  const unsigned short* bgsrc[2];
  const unsigned short* busrc[2];
  #pragma unroll
  for (int j = 0; j < 2; ++j){
    int cj = j*256 + tid;
    int r  = cj >> 3;
    int sw = ((cj & 7) ^ (r & 7)) * 8;
    bgsrc[j] = gw + ((size_t)e*FF + n0 + r)*HD + sw;
    busrc[j] = uw + ((size_t)e*FF + n0 + r)*HD + sw;
  }

  f32x4 accg[4][2] = {};
  f32x4 accu[4][2] = {};

  for (int ks = 0; ks < HD/64; ++ks){
    #pragma unroll
    for (int j = 0; j < 4; ++j)
      gload16(asrc[j] + ks*64, &As[(j*256+tid)*8]);
    #pragma unroll
    for (int j = 0; j < 2; ++j){
      gload16(bgsrc[j] + ks*64, &Bg[(j*256+tid)*8]);
      gload16(busrc[j] + ks*64, &Bu[(j*256+tid)*8]);
    }
    __syncthreads();
    #pragma unroll
    for (int kk = 0; kk < 2; ++kk){
      bf16x8 a[4], fg[2], fu[2];
      #pragma unroll
      for (int m = 0; m < 4; ++m){
        int r = wm*64 + m*16 + ar;
        a[m] = *(const bf16x8*)&As[r*64 + (((kk*4 + kb) ^ (r & 7))*8)];
      }
      #pragma unroll
      for (int n = 0; n < 2; ++n){
        int rf = wn*32 + n*16 + ar;
        int o  = rf*64 + (((kk*4 + kb) ^ (rf & 7))*8);
        fg[n] = *(const bf16x8*)&Bg[o];
        fu[n] = *(const bf16x8*)&Bu[o];
      }
      #pragma unroll
      for (int m = 0; m < 4; ++m){
        #pragma unroll
        for (int n = 0; n < 2; ++n){
          accg[m][n] = __builtin_amdgcn_mfma_f32_16x16x32_bf16(a[m], fg[n], accg[m][n], 0, 0, 0);
          accu[m][n] = __builtin_amdgcn_mfma_f32_16x16x32_bf16(a[m], fu[n], accu[m][n], 0, 0, 0);
        }
      }
    }
    __syncthreads();
  }

  #pragma unroll
  for (int m = 0; m < 4; ++m){
    #pragma unroll
    for (int n = 0; n < 2; ++n){
      int fcol = n0 + wn*32 + n*16 + ar;
      #pragma unroll
      for (int i = 0; i < 4; ++i){
        int gr = m0 + wm*64 + m*16 + kb*4 + i;
        if (gr < c){
          float g = accg[m][n][i];
          float u = accu[m][n][i];
          float s = g / (1.0f + expf(-g));
          hbuf[(size_t)(off_e + gr)*FF + fcol] = f2bf(s * u);
        }
      }
    }
  }
}

// ---------------- stage-2: y = h @ downT, grouped ----------------
// BM=128 x BN=128, BK=64, 4 waves (2x2, wave 64x64), same structure.
__global__ __launch_bounds__(256, 3) void gemm_down(
    const unsigned short* __restrict__ hbuf,
    const unsigned short* __restrict__ dw,
    const int* __restrict__ cnt, const int* __restrict__ offs,
    unsigned short* __restrict__ ybuf)
{
  // 1D grid = 32 * (HD/128) * NE = 4096, XCD swizzle
  const int cpx = gridDim.x >> 3;
  const int bid = blockIdx.x;
  const int nid = (bid & 7) * cpx + (bid >> 3);
  const int mb   = nid & 31;
  const int rest = nid >> 5;
  const int nb   = rest & 7;
  const int e    = rest >> 3;

  const int c  = cnt[e];
  const int m0 = mb * 128;
  if (m0 >= c) return;
  const int n0 = nb * 128;
  const int off_e = offs[e];

  __shared__ unsigned short As[128*64];
  __shared__ unsigned short Bs[128*64];

  const int tid  = threadIdx.x;
  const int lane = tid & 63;
  const int wid  = tid >> 6;
  const int ar = lane & 15;
  const int kb = lane >> 4;
  const int wm = wid >> 1;
  const int wn = wid & 1;

  const unsigned short* asrc[4];
  const unsigned short* bsrc[4];
  #pragma unroll
  for (int j = 0; j < 4; ++j){
    int cj = j*256 + tid;
    int r  = cj >> 3;
    int sw = ((cj & 7) ^ (r & 7)) * 8;
    int rm = m0 + r; if (rm > c-1) rm = c-1;
    asrc[j] = hbuf + (size_t)(off_e + rm)*FF + sw;
    bsrc[j] = dw + ((size_t)e*HD + n0 + r)*FF + sw;
  }

  f32x4 acc[4][4] = {};

  for (int ks = 0; ks < FF/64; ++ks){
    #pragma unroll
    for (int j = 0; j < 4; ++j){
      gload16(asrc[j] + ks*64, &As[(j*256+tid)*8]);
      gload16(bsrc[j] + ks*64, &Bs[(j*256+tid)*8]);
    }
    __syncthreads();
    #pragma unroll
    for (int kk = 0; kk < 2; ++kk){
      bf16x8 a[4], b[4];
      #pragma unroll
      for (int m = 0; m < 4; ++m){
        int r = wm*64 + m*16 + ar;
        a[m] = *(const bf16x8*)&As[r*64 + (((kk*4 + kb) ^ (r & 7))*8)];
      }
      #pragma unroll
      for (int n = 0; n < 4; ++n){
        int r = wn*64 + n*16 + ar;
        b[n] = *(const bf16x8*)&Bs[r*64 + (((kk*4 + kb) ^ (r & 7))*8)];
      }
      #pragma unroll
      for (int m = 0; m < 4; ++m){
        #pragma unroll
        for (int n = 0; n < 4; ++n){
          acc[m][n] = __builtin_amdgcn_mfma_f32_16x16x32_bf16(a[m], b[n], acc[m][n], 0, 0, 0);
        }
      }
    }
    __syncthreads();
  }

  #pragma unroll
  for (int m = 0; m < 4; ++m){
    #pragma unroll
    for (int n = 0; n < 4; ++n){
      int col = n0 + wn*64 + n*16 + ar;
      #pragma unroll
      for (int i = 0; i < 4; ++i){
        int gr = m0 + wm*64 + m*16 + kb*4 + i;
        if (gr < c){
          ybuf[(size_t)(off_e + gr)*HD + col] = f2bf(acc[m][n][i]);
        }
      }
    }
  }
}

// ---------------- combine ----------------
__global__ __launch_bounds__(256) void combine_kernel(
    const unsigned short* __restrict__ ybuf,
    const int* __restrict__ slot_of, const float* __restrict__ topk_w,
    float* __restrict__ out)
{
  const int t   = blockIdx.x;
  const int tid = threadIdx.x;
  const int c0  = tid * 4;
  float4 acc = {0.f, 0.f, 0.f, 0.f};
  #pragma unroll
  for (int k = 0; k < TOPK; ++k){
    int slot = slot_of[t*TOPK + k];
    float w  = topk_w[t*TOPK + k];
    ushort4 v = *(const ushort4*)&ybuf[(size_t)slot*HD + c0];
    acc.x += w * bf2f(v.x);
    acc.y += w * bf2f(v.y);
    acc.z += w * bf2f(v.z);
    acc.w += w * bf2f(v.w);
  }
  ((float4*)out)[(size_t)t*(HD/4) + tid] = acc;
}

extern "C" void kernel_launch(void* const* d_in, const int* in_sizes, int n_in,
                              void* d_out, int out_size, void* d_ws, size_t ws_size,
                              hipStream_t stream)
{
  const float* x  = (const float*)d_in[0];
  const float* rw = (const float*)d_in[1];
  const float* gw = (const float*)d_in[2];
  const float* uw = (const float*)d_in[3];
  const float* dw = (const float*)d_in[4];
  float* out = (float*)d_out;

  char* ws = (char*)d_ws;
  size_t off = 0;
  auto alloc = [&](size_t b) -> void* {
    void* p = ws + off;
    off += (b + 255) & ~(size_t)255;
    return p;
  };

  unsigned short* gwb  = (unsigned short*)alloc((size_t)NE*FF*HD*2);
  unsigned short* uwb  = (unsigned short*)alloc((size_t)NE*FF*HD*2);
  unsigned short* dwb  = (unsigned short*)alloc((size_t)NE*HD*FF*2);
  unsigned short* xbf  = (unsigned short*)alloc((size_t)T_TOK*HD*2);
  unsigned short* hbuf = (unsigned short*)alloc((size_t)NPAIR*FF*2);
  unsigned short* ybuf = (unsigned short*)alloc((size_t)NPAIR*HD*2);
  int*   tki   = (int*)alloc((size_t)T_TOK*TOPK*4);
  float* tkw   = (float*)alloc((size_t)T_TOK*TOPK*4);
  int*   rowsb = (int*)alloc((size_t)NPAIR*4);
  int*   slotf = (int*)alloc((size_t)NPAIR*4);
  int*   cntb  = (int*)alloc(NE*4);
  int*   offsb = (int*)alloc(NE*4);

  // convert gate+up (even blocks) + router (odd blocks)
  convgu_router_kernel<<<8192, 256, 0, stream>>>(gw, uw, gwb, uwb,
                                                 x, rw, xbf, tki, tkw);
  lists_kernel<<<NE, 256, 0, stream>>>(tki, rowsb, slotf, cntb, offsb);

  // gateup GEMM + down_w conversion riding along (role-split grid)
  gemm_gateup<<<32*(FF/64)*NE + 2048, 256, 0, stream>>>(
      xbf, gwb, uwb, rowsb, cntb, offsb, hbuf, dw, dwb);
  gemm_down<<<32*(HD/128)*NE, 256, 0, stream>>>(hbuf, dwb, cntb, offsb, ybuf);

  combine_kernel<<<T_TOK, 256, 0, stream>>>(ybuf, slotf, tkw, out);
}